// Round 1
// baseline (192.482 us; speedup 1.0000x reference)
//
#include <hip/hip_runtime.h>
#include <math.h>

#define TOKENS  32768
#define HIDDEN  2048
#define EXPERTS 64
#define TOPK    8

// ---------------------------------------------------------------------------
// Kernel 1: transpose weight [64][2048] -> wT [2048][64] (into d_ws, 512 KB)
// so that per-k the 64 expert weights are consecutive -> scalar-loadable.
// ---------------------------------------------------------------------------
__global__ void wt_transpose(const float* __restrict__ W, float* __restrict__ wT) {
    int i = blockIdx.x * 256 + threadIdx.x;   // 0..131071
    int k = i >> 6;
    int e = i & 63;
    wT[i] = W[e * HIDDEN + k];
}

// ---------------------------------------------------------------------------
// Kernel 2: router. Block = 256 threads = 4 waves; block owns 64 tokens.
// lane t <-> token (blk*64+t); wave w handles K-slice [w*512, w*512+512).
// Each lane keeps 64 fp32 expert accumulators; weights come in via s_load
// (wave-uniform wT row), A via per-lane float4 loads (L1-friendly).
// Epilogue: LDS reduce over 4 waves + bias, per-lane top-8 + softmax,
// scatter via LDS, coalesced float4 score writes. Indices stored as floats.
// ---------------------------------------------------------------------------
__global__ __launch_bounds__(256, 2)
void router_kernel(const float* __restrict__ A,
                   const float* __restrict__ wT,
                   const float* __restrict__ bias,
                   float* __restrict__ out) {
    __shared__ float smem[16384];            // 64 KB: 4 x [64 experts][64 tokens]
    const int tid = threadIdx.x;
    const int w   = tid >> 6;                // wave 0..3
    const int t   = tid & 63;                // lane == token-in-block
    const int blk = blockIdx.x;
    const int token = blk * 64 + t;

    float acc[64];
    #pragma unroll
    for (int e = 0; e < 64; ++e) acc[e] = 0.f;

    const int k0 = w * 512;
    const float* a_row = A + (size_t)token * HIDDEN + k0;

    float4 av = *(const float4*)(a_row);
    #pragma unroll 1
    for (int kk = 0; kk < 512; kk += 4) {
        // prefetch next A chunk so vmem latency hides under the 256 FMAs
        float4 nxt = make_float4(0.f, 0.f, 0.f, 0.f);
        if (kk + 4 < 512) nxt = *(const float4*)(a_row + kk + 4);

        // wave-uniform wT row base -> scalar loads
        int kb = __builtin_amdgcn_readfirstlane(k0 + kk);
        const float* w0 = wT + (size_t)kb * 64;

        float aj;
        aj = av.x;
        #pragma unroll
        for (int e = 0; e < 64; ++e) acc[e] = fmaf(aj, w0[e], acc[e]);
        aj = av.y;
        #pragma unroll
        for (int e = 0; e < 64; ++e) acc[e] = fmaf(aj, w0[64 + e], acc[e]);
        aj = av.z;
        #pragma unroll
        for (int e = 0; e < 64; ++e) acc[e] = fmaf(aj, w0[128 + e], acc[e]);
        aj = av.w;
        #pragma unroll
        for (int e = 0; e < 64; ++e) acc[e] = fmaf(aj, w0[192 + e], acc[e]);

        av = nxt;
    }

    // ---- write per-wave partials: smem[w*4096 + e*64 + t] (conflict-free) ----
    float* part = smem + w * 4096;
    #pragma unroll
    for (int e = 0; e < 64; ++e) part[e * 64 + t] = acc[e];
    __syncthreads();

    // ---- reduce 4 waves + bias, in-place into region 0 ----
    #pragma unroll
    for (int q = 0; q < 16; ++q) {
        int i = tid + 256 * q;               // i = e*64 + tok
        float v = smem[i] + smem[4096 + i] + smem[8192 + i] + smem[12288 + i];
        v += bias[i >> 6];
        smem[i] = v;                         // each slot touched by exactly one thread
    }
    __syncthreads();

    // scatter area aliases regions 2..3 (free after reduce): [64 tok][65] padded
    float* scat = smem + 8192;
    for (int i = tid; i < 64 * 65; i += 256) scat[i] = 0.f;

    float tvals[TOPK]; int tix[TOPK]; float probs[TOPK];
    #pragma unroll
    for (int j = 0; j < TOPK; ++j) { tvals[j] = 0.f; tix[j] = 0; probs[j] = 0.f; }

    const bool active = (tid < 64);
    if (active) {
        float v[64];
        #pragma unroll
        for (int e = 0; e < 64; ++e) v[e] = smem[e * 64 + t];

        unsigned long long chosen = 0ull;
        #pragma unroll
        for (int j = 0; j < TOPK; ++j) {
            float best = -INFINITY; int bi = 0;
            #pragma unroll
            for (int e = 0; e < 64; ++e) {
                bool ok = ((chosen >> e) & 1ull) == 0ull;   // skip already chosen
                if (ok && v[e] > best) { best = v[e]; bi = e; }  // strict > : lowest idx on tie
            }
            chosen |= (1ull << bi);
            tvals[j] = best; tix[j] = bi;
        }
        // softmax over the selected 8 (tvals[0] is the max)
        float m = tvals[0];
        float s = 0.f;
        #pragma unroll
        for (int j = 0; j < TOPK; ++j) { probs[j] = __expf(tvals[j] - m); s += probs[j]; }
        float inv = 1.f / s;
        #pragma unroll
        for (int j = 0; j < TOPK; ++j) probs[j] *= inv;
    }
    __syncthreads();   // zero-fill of scat complete

    if (active) {
        #pragma unroll
        for (int j = 0; j < TOPK; ++j) scat[t * 65 + tix[j]] = probs[j];
        // indices output (stored as float values; exact for 0..63)
        float* oidx = out + (size_t)TOKENS * EXPERTS;
        #pragma unroll
        for (int j = 0; j < TOPK; ++j) oidx[(size_t)token * TOPK + j] = (float)tix[j];
    }
    __syncthreads();   // scatter complete

    // ---- coalesced score write: 64 tokens x 64 experts = 4096 floats ----
    float* oscore = out + (size_t)blk * 4096;
    #pragma unroll
    for (int q = 0; q < 4; ++q) {
        int i = tid + 256 * q;               // float4 index 0..1023
        int tok = i >> 4;
        int e0  = (i & 15) * 4;
        float4 vv;
        vv.x = scat[tok * 65 + e0 + 0];
        vv.y = scat[tok * 65 + e0 + 1];
        vv.z = scat[tok * 65 + e0 + 2];
        vv.w = scat[tok * 65 + e0 + 3];
        *(float4*)(oscore + (size_t)i * 4) = vv;
    }
}

extern "C" void kernel_launch(void* const* d_in, const int* in_sizes, int n_in,
                              void* d_out, int out_size, void* d_ws, size_t ws_size,
                              hipStream_t stream) {
    const float* A    = (const float*)d_in[0];   // [32768, 2048] fp32
    const float* W    = (const float*)d_in[1];   // [64, 2048] fp32
    const float* bias = (const float*)d_in[2];   // [64] fp32
    float* out = (float*)d_out;                  // scores (32768*64) ++ idx (32768*8)
    float* wT  = (float*)d_ws;                   // needs 2048*64*4 = 512 KB scratch

    // 1) transpose weight into workspace
    wt_transpose<<<512, 256, 0, stream>>>(W, wT);
    // 2) fused router: logits + top-8 + softmax + scatter
    router_kernel<<<TOKENS / 64, 256, 0, stream>>>(A, wT, bias, out);
}